// Round 4
// baseline (140.537 us; speedup 1.0000x reference)
//
#include <hip/hip_runtime.h>
#include <math.h>

#define T_   100
#define D_   50
#define BS_  2
#define CH_  100
#define RI_  12
#define RC_  16
#define KNN_ 3
#define NJ_  (RI_ + RC_)              // 28
#define QD_  (CH_ * NJ_)              // 2800

// ---------------------------------------------------------------------------
// Kernel 1: one block per (b, t). key[s] = 2*dot(x[:,t],x[:,s]) - cube[s]
// (-cube[t] is a uniform shift). x read directly from global (80 KB, L2-hot):
// x[c,s] coalesced, x[c,t] uniform/scalar. Top-3 via wave-0 butterfly argmax
// (tie -> lowest index, matching lax.top_k). ctx[b,t,k] = mean_c x[b,c,idx_k].
// ---------------------------------------------------------------------------
__global__ __launch_bounds__(128) void ctx_kernel(const float* __restrict__ x,
                                                  float* __restrict__ ctx) {
    __shared__ float cm[T_];
    __shared__ float va[128];

    const int b = blockIdx.x / T_;
    const int t = blockIdx.x - b * T_;
    const float* xb = x + b * CH_ * T_;
    const int s = threadIdx.x;

    float key = -INFINITY;
    if (s < T_) {
        float dot = 0.f, cube = 0.f, colsum = 0.f;
        #pragma unroll 10
        for (int c = 0; c < CH_; ++c) {
            float vv = xb[c * T_ + s];   // coalesced across lanes
            float vt = xb[c * T_ + t];   // uniform -> scalar load
            dot    += vv * vt;
            cube   += vv * vv * vv;
            colsum += vv;
        }
        key = 2.f * dot - cube;
        cm[s] = colsum * (1.0f / (float)CH_);
    }
    va[threadIdx.x] = key;
    __syncthreads();

    if (threadIdx.x < 64) {              // wave 0 only
        const int l = threadIdx.x;
        const float c0v = va[l];
        const float c1v = va[l + 64];    // -inf for s >= 100
        int sel0 = -100, sel1 = -100;
        for (int k = 0; k < KNN_; ++k) {
            float v0 = (l == sel0 || l == sel1) ? -INFINITY : c0v;
            float v1 = (l + 64 == sel0 || l + 64 == sel1) ? -INFINITY : c1v;
            float bv; int bi;
            if (v1 > v0) { bv = v1; bi = l + 64; } else { bv = v0; bi = l; }
            #pragma unroll
            for (int off = 32; off > 0; off >>= 1) {
                float ov = __shfl_xor(bv, off);
                int   oi = __shfl_xor(bi, off);
                if (ov > bv || (ov == bv && oi < bi)) { bv = ov; bi = oi; }
            }
            if (l == 0) ctx[(b * T_ + t) * KNN_ + k] = cm[bi];
            if (k == 0) sel0 = bi; else sel1 = bi;
        }
    }
}

// ---------------------------------------------------------------------------
// Kernel 2: one block per (b, c, j) = one contiguous 20 KB output plane
// [du][s]. Anchors are ANALYTIC: when s+du < 100,
//   start = s - (du+1)/2, end = s + du + (du+1)/2
//   coord = s + g,  g = jsc*(2du+1) - (du+1)*0.5   (per-(j,du) constant)
// else start=end=0 -> coord=0 (valid, frac=0 -> value fr[0]).
// No anchor loads, no LDS. Value reads: coalesced global dword loads on a
// 400 B (or 12 B) L1-resident row. Stores: float4, each block's writes form
// one contiguous 20 KB span -> negligible partial-cacheline RMW.
// ---------------------------------------------------------------------------
__global__ __launch_bounds__(256) void out_kernel(const float* __restrict__ x,
                                                  const float* __restrict__ ctx,
                                                  float* __restrict__ out) {
    const int j = blockIdx.x % NJ_;
    const int c = (blockIdx.x / NJ_) % CH_;
    const int b = blockIdx.x / (NJ_ * CH_);

    const bool inner = (j < RI_);
    const float jsc = inner ? ((float)j + 0.5f) * (1.0f / (float)RI_)
                            : ((float)(j - RI_) + 0.5f) * (1.0f / (float)RC_);
    const float Lf  = inner ? (float)T_ : (float)KNN_;
    const int   Lm1 = inner ? (T_ - 1) : (KNN_ - 1);
    const float* __restrict__ fr = inner ? (x + (b * CH_ + c) * T_)
                                         : (ctx + (b * T_ + c) * KNN_);
    float* __restrict__ ob = out + (size_t)((b * QD_ + c * NJ_ + j) * D_) * T_;

    for (int i4 = threadIdx.x; i4 < D_ * (T_ / 4); i4 += 256) {   // 1250
        const int du = i4 / (T_ / 4);
        const int s0 = (i4 - du * (T_ / 4)) * 4;

        // per-(j,du) constants
        const float g = jsc * (float)(2 * du + 1) - (float)(du + 1) * 0.5f;
        const float fg = floorf(g);
        const float fracg = g - fg;
        const int flo = (int)fg;

        float res[4];
        #pragma unroll
        for (int i = 0; i < 4; ++i) {
            const int s = s0 + i;
            const bool aok = (s + du) < T_;          // anchor-valid
            const float coord = aok ? (float)s + g : 0.0f;
            const bool valid = (coord >= -1.0f) && (coord <= Lf);
            const float f = aok ? fracg : 0.0f;
            int idx = aok ? s + flo : 0;
            int lo = idx < 0 ? 0 : (idx > Lm1 ? Lm1 : idx);
            int hi = lo + 1 > Lm1 ? Lm1 : lo + 1;
            const float v = fr[lo] * (1.0f - f) + fr[hi] * f;
            res[i] = valid ? v : 0.0f;
        }
        *(float4*)(ob + du * T_ + s0) = make_float4(res[0], res[1], res[2], res[3]);
    }
}

extern "C" void kernel_launch(void* const* d_in, const int* in_sizes, int n_in,
                              void* d_out, int out_size, void* d_ws, size_t ws_size,
                              hipStream_t stream) {
    const float* x = (const float*)d_in[0];
    // d_in[1] (anchors) is reproduced analytically; d_in[2] (index) unused.
    float* ctx = (float*)d_ws;     // 2*100*3 = 600 floats
    float* out = (float*)d_out;

    ctx_kernel<<<BS_ * T_, 128, 0, stream>>>(x, ctx);

    const int blocks = BS_ * CH_ * NJ_;   // 5600
    out_kernel<<<blocks, 256, 0, stream>>>(x, ctx, out);
}

// Round 6
// 136.812 us; speedup vs baseline: 1.0272x; 1.0272x over previous
//
#include <hip/hip_runtime.h>
#include <math.h>

#define T_   100
#define D_   50
#define BS_  2
#define CH_  100
#define RI_  12
#define RC_  16
#define KNN_ 3
#define NJ_  (RI_ + RC_)              // 28
#define QD_  (CH_ * NJ_)              // 2800

// ---------------------------------------------------------------------------
// Kernel 1: one block per (b, t). key[s] = 2*dot(x[:,t],x[:,s]) - cube[s]
// (-cube[t] is a uniform shift). x read directly from global (80 KB, L2-hot).
// Top-3 via wave-0 butterfly argmax (tie -> lowest index = lax.top_k).
// ctx[b,t,k] = mean_c x[b,c,idx_k].
// ---------------------------------------------------------------------------
__global__ __launch_bounds__(128) void ctx_kernel(const float* __restrict__ x,
                                                  float* __restrict__ ctx) {
    __shared__ float cm[T_];
    __shared__ float va[128];

    const int b = blockIdx.x / T_;
    const int t = blockIdx.x - b * T_;
    const float* xb = x + b * CH_ * T_;
    const int s = threadIdx.x;

    float key = -INFINITY;
    if (s < T_) {
        float dot = 0.f, cube = 0.f, colsum = 0.f;
        #pragma unroll 10
        for (int c = 0; c < CH_; ++c) {
            float vv = xb[c * T_ + s];   // coalesced across lanes
            float vt = xb[c * T_ + t];   // uniform -> scalar load
            dot    += vv * vt;
            cube   += vv * vv * vv;
            colsum += vv;
        }
        key = 2.f * dot - cube;
        cm[s] = colsum * (1.0f / (float)CH_);
    }
    va[threadIdx.x] = key;
    __syncthreads();

    if (threadIdx.x < 64) {              // wave 0 only
        const int l = threadIdx.x;
        const float c0v = va[l];
        const float c1v = va[l + 64];    // -inf for s >= 100
        int sel0 = -100, sel1 = -100;
        for (int k = 0; k < KNN_; ++k) {
            float v0 = (l == sel0 || l == sel1) ? -INFINITY : c0v;
            float v1 = (l + 64 == sel0 || l + 64 == sel1) ? -INFINITY : c1v;
            float bv; int bi;
            if (v1 > v0) { bv = v1; bi = l + 64; } else { bv = v0; bi = l; }
            #pragma unroll
            for (int off = 32; off > 0; off >>= 1) {
                float ov = __shfl_xor(bv, off);
                int   oi = __shfl_xor(bi, off);
                if (ov > bv || (ov == bv && oi < bi)) { bv = ov; bi = oi; }
            }
            if (l == 0) ctx[(b * T_ + t) * KNN_ + k] = cm[bi];
            if (k == 0) sel0 = bi; else sel1 = bi;
        }
    }
}

// select w[o], o in [0,8)
__device__ __forceinline__ float sel8(const float4& A, const float4& B, int o) {
    float t0 = (o & 1) ? A.y : A.x;
    float t1 = (o & 1) ? A.w : A.z;
    float t2 = (o & 1) ? B.y : B.x;
    float t3 = (o & 1) ? B.w : B.z;
    float u0 = (o & 2) ? t1 : t0;
    float u1 = (o & 2) ? t3 : t2;
    return (o & 4) ? u1 : u0;
}

// ---------------------------------------------------------------------------
// Kernel 2: one block per (b, c, j) = one contiguous 20 KB output plane
// [du][s]. Anchors analytic: coord = s + g, g = jsc*(2du+1) - (du+1)*0.5
// (per-(j,du) constant); s+du >= 100 -> coord = 0 -> fr[0].
// Reference clip order: lo = clip(floor(coord),0,L-1); hi = clip(lo+1,0,L-1)
// — lo and hi are selected INDEPENDENTLY from an aligned 8-float window
// (2 vmem/item). Window proof: a0 = min(max(base,0)&~3, 92); lo-a0,
// hi-a0 in [0,7] for all cases (incl. base<0 -> lo=0,hi=1; base>92 ->
// clamps to 99). Context (j>=12): 3-element row in registers, 0 loads/item.
// ---------------------------------------------------------------------------
__global__ __launch_bounds__(256) void out_kernel(const float* __restrict__ x,
                                                  const float* __restrict__ ctx,
                                                  float* __restrict__ out) {
    const int j = blockIdx.x % NJ_;
    const int c = (blockIdx.x / NJ_) % CH_;
    const int b = blockIdx.x / (NJ_ * CH_);

    const bool inner = (j < RI_);
    const float jsc = inner ? ((float)j + 0.5f) * (1.0f / (float)RI_)
                            : ((float)(j - RI_) + 0.5f) * (1.0f / (float)RC_);
    const float* __restrict__ fr = inner ? (x + (b * CH_ + c) * T_)
                                         : (ctx + (b * T_ + c) * KNN_);
    float* __restrict__ ob = out + (size_t)((b * QD_ + c * NJ_ + j) * D_) * T_;

    // context row (and fr[0] for the anchor-invalid region) in registers
    float cr0 = fr[0], cr1 = 0.f, cr2 = 0.f;
    if (!inner) { cr1 = fr[1]; cr2 = fr[2]; }

    for (int i4 = threadIdx.x; i4 < D_ * (T_ / 4); i4 += 256) {   // 1250
        const int du = i4 / (T_ / 4);
        const int s0 = (i4 - du * (T_ / 4)) * 4;

        const float g = jsc * (float)(2 * du + 1) - (float)(du + 1) * 0.5f;
        const float fg = floorf(g);
        const float fracg = g - fg;     // == coord - floor(coord), s integral
        const float omf = 1.0f - fracg;
        const int base = s0 + (int)fg;  // floor(coord) for lane i is base + i

        float res[4];
        if (inner) {
            int bcl = base < 0 ? 0 : base;
            int a0 = bcl & ~3;
            a0 = a0 > 92 ? 92 : a0;
            const float4 wA = *(const float4*)(fr + a0);
            const float4 wB = *(const float4*)(fr + a0 + 4);
            #pragma unroll
            for (int i = 0; i < 4; ++i) {
                const int s = s0 + i;
                const bool aok = (s + du) < T_;
                const float coord = (float)s + g;
                const bool valid = (coord >= -1.0f) && (coord <= (float)T_);
                int lo = base + i;
                lo = lo < 0 ? 0 : (lo > 99 ? 99 : lo);
                int hi = lo + 1 > 99 ? 99 : lo + 1;     // clip AFTER lo-clip
                const float vl = sel8(wA, wB, lo - a0);
                const float vh = sel8(wA, wB, hi - a0);
                const float bl = vl * omf + vh * fracg;
                res[i] = aok ? (valid ? bl : 0.0f) : cr0;
            }
        } else {
            #pragma unroll
            for (int i = 0; i < 4; ++i) {
                const int s = s0 + i;
                const bool aok = (s + du) < T_;
                const float coord = (float)s + g;
                const bool valid = (coord >= -1.0f) && (coord <= (float)KNN_);
                int lo = base + i;
                lo = lo < 0 ? 0 : (lo > 2 ? 2 : lo);
                const float vL = lo == 0 ? cr0 : (lo == 1 ? cr1 : cr2);
                const float vH = lo == 0 ? cr1 : cr2;   // clip(lo+1,0,2)
                const float bl = vL * omf + vH * fracg;
                res[i] = aok ? (valid ? bl : 0.0f) : cr0;
            }
        }
        *(float4*)(ob + du * T_ + s0) = make_float4(res[0], res[1], res[2], res[3]);
    }
}

extern "C" void kernel_launch(void* const* d_in, const int* in_sizes, int n_in,
                              void* d_out, int out_size, void* d_ws, size_t ws_size,
                              hipStream_t stream) {
    const float* x = (const float*)d_in[0];
    // d_in[1] (anchors) reproduced analytically; d_in[2] (index) unused.
    float* ctx = (float*)d_ws;     // 2*100*3 = 600 floats
    float* out = (float*)d_out;

    ctx_kernel<<<BS_ * T_, 128, 0, stream>>>(x, ctx);

    const int blocks = BS_ * CH_ * NJ_;   // 5600
    out_kernel<<<blocks, 256, 0, stream>>>(x, ctx, out);
}